// Round 3
// baseline (329.700 us; speedup 1.0000x reference)
//
#include <hip/hip_runtime.h>

#define T_STEPS 100
#define BATCH 256
#define NIN 784
#define N0 64
#define N1 64
#define N2 10
#define CHUNK (BATCH*N0 + BATCH*N1 + BATCH*N2)   // 35328
#define NKQ 196            // float4 columns per W0 row (784/4)
#define SKQ 28             // float4 columns staged per stage
#define NSTAGE 7           // 196 / 28
#define WROW 29            // padded LDS row length in float4 (bank-conflict-free)

// One block per batch element. Phase A: GEMM0 with X via scalar loads
// (wave-uniform rows) and W0 via double-buffered LDS. Phase B: LIF scans +
// GEMM1/GEMM2 entirely LDS-resident.
__global__ __launch_bounds__(256) void snn_kernel(
    const float* __restrict__ X, const float* __restrict__ W0,
    const float* __restrict__ b0,
    const float* __restrict__ W1, const float* __restrict__ b1,
    const float* __restrict__ W2, const float* __restrict__ b2,
    float* __restrict__ out) {

  // 2 x (64 rows x 29 float4) = 3712 float4 = 59392 B
  __shared__ float4 smem[2 * 64 * WROW];

  const int b   = blockIdx.x;
  const int tid = threadIdx.x;
  const int j   = tid & 63;               // output column (per-lane)
  const int tq  = tid >> 6;               // wave id 0..3 -> t-quarter
  const int t0  = __builtin_amdgcn_readfirstlane(tq * 25);  // force SGPR

  // 25 wave-uniform X row pointers (scalar-load path)
  const float* xrow[25];
#pragma unroll
  for (int tl = 0; tl < 25; ++tl)
    xrow[tl] = X + ((size_t)(t0 + tl) * BATCH + b) * NIN;

  const float4* W0f4 = (const float4*)W0;

  float acc[25];
#pragma unroll
  for (int tl = 0; tl < 25; ++tl) acc[tl] = 0.0f;

  // ---- prologue: stage 0 of W0 into buffer 0
#pragma unroll
  for (int i = 0; i < 7; ++i) {
    int f = tid + i * 256;                // 0..1791 over 64 j x 28 kq
    int jj = f / SKQ, kql = f % SKQ;
    smem[jj * WROW + kql] = W0f4[(size_t)jj * NKQ + kql];
  }
  __syncthreads();

  float4 pre[7];
  for (int s = 0; s < NSTAGE; ++s) {
    const int cur = s & 1;
    // prefetch next W0 stage into registers (in flight during compute)
    if (s + 1 < NSTAGE) {
#pragma unroll
      for (int i = 0; i < 7; ++i) {
        int f = tid + i * 256;
        int jj = f / SKQ, kql = f % SKQ;
        pre[i] = W0f4[(size_t)jj * NKQ + (s + 1) * SKQ + kql];
      }
    }
    // compute this stage: 28 kq x 25 t x 4 k
    const float4* Wt = smem + cur * 64 * WROW;
    const int kbase = s * (SKQ * 4);
#pragma unroll 4
    for (int kq = 0; kq < SKQ; ++kq) {
      float4 w = Wt[j * WROW + kq];       // per-lane b128, conflict-free
#pragma unroll
      for (int tl = 0; tl < 25; ++tl) {
        float4 xs = *(const float4*)(xrow[tl] + kbase + kq * 4);  // uniform -> s_load
        acc[tl] = fmaf(xs.w, w.w, fmaf(xs.z, w.z,
                  fmaf(xs.y, w.y, fmaf(xs.x, w.x, acc[tl]))));
      }
    }
    // write prefetched stage into the other buffer
    if (s + 1 < NSTAGE) {
      float4* Wn = smem + (cur ^ 1) * 64 * WROW;
#pragma unroll
      for (int i = 0; i < 7; ++i) {
        int f = tid + i * 256;
        int jj = f / SKQ, kql = f % SKQ;
        Wn[jj * WROW + kql] = pre[i];
      }
      __syncthreads();
    }
  }
  __syncthreads();   // phase A done; smem is re-aliased below

  // ---------------- phase B: LDS aliases ----------------
  float* smf = (float*)smem;
  float (*bufA)[64] = (float(*)[64])smf;                        // 6400 floats
  float (*sW1t)[66] = (float(*)[66])(smf + 6400);               // 4224 floats
  float (*sW2)[68]  = (float(*)[68])(smf + 6400 + 4224);        // 680 floats
  float (*sI2)[N2]  = (float(*)[N2])(smf + 6400 + 4224 + 680);  // 1000 floats

  float* outSpk = out;                        // [T][B][10]
  float* laySpk = out + T_STEPS * BATCH * N2; // [T][35328]

  // ---- I0 (+bias) -> bufA
  {
    const float bj = b0[j];
#pragma unroll
    for (int tl = 0; tl < 25; ++tl) bufA[tq * 25 + tl][j] = acc[tl] + bj;
  }
  __syncthreads();

  // ---- scan0 (wave 0) overlapped with W1/W2 staging (waves 1-3)
  if (tq == 0) {
    float v = 0.0f;
    for (int t = 0; t < T_STEPS; ++t) {
      float icur = bufA[t][j];
      v = v + 0.05f * ((0.0f - v) + icur);
      float z = (v > 1.0f) ? 1.0f : 0.0f;
      v -= z;
      bufA[t][j] = z;
    }
  } else {
    for (int idx = tid - 64; idx < 64 * 16; idx += 192) {
      int i = idx >> 4, jv = idx & 15;
      float4 w = *(const float4*)(W1 + (size_t)i * 64 + jv * 4);
      sW1t[jv * 4 + 0][i] = w.x;
      sW1t[jv * 4 + 1][i] = w.y;
      sW1t[jv * 4 + 2][i] = w.z;
      sW1t[jv * 4 + 3][i] = w.w;
    }
    for (int idx = tid - 64; idx < N2 * 16; idx += 192) {
      int o = idx >> 4, jv = idx & 15;
      *(float4*)&sW2[o][jv * 4] = *(const float4*)(W2 + (size_t)o * 64 + jv * 4);
    }
  }
  __syncthreads();

  // ---- z0 -> layer_spikes
  for (int idx = tid; idx < T_STEPS * 16; idx += 256) {
    int t = idx >> 4, jv = idx & 15;
    *(float4*)(laySpk + (size_t)t * CHUNK + b * 64 + jv * 4) =
        *(const float4*)&bufA[t][jv * 4];
  }

  // ---- GEMM1: I1[t][i] = sum_j z0[t][j] * W1[i][j] + b1[i]
  {
    const float bias = b1[j];
#pragma unroll
    for (int tl = 0; tl < 25; ++tl) acc[tl] = bias;
    const int tb = tq * 25;
    for (int jq = 0; jq < 16; ++jq) {
      float w0 = sW1t[jq * 4 + 0][j];
      float w1 = sW1t[jq * 4 + 1][j];
      float w2 = sW1t[jq * 4 + 2][j];
      float w3 = sW1t[jq * 4 + 3][j];
#pragma unroll
      for (int tl = 0; tl < 25; ++tl) {
        float4 z = *(const float4*)&bufA[tb + tl][jq * 4];
        acc[tl] += z.x * w0;
        acc[tl] += z.y * w1;
        acc[tl] += z.z * w2;
        acc[tl] += z.w * w3;
      }
    }
  }
  __syncthreads();            // all z0 reads complete
#pragma unroll
  for (int tl = 0; tl < 25; ++tl) bufA[tq * 25 + tl][j] = acc[tl];
  __syncthreads();

  // ---- scan1
  if (tq == 0) {
    float v = 0.0f;
    for (int t = 0; t < T_STEPS; ++t) {
      float icur = bufA[t][j];
      v = v + 0.05f * ((0.0f - v) + icur);
      float z = (v > 1.0f) ? 1.0f : 0.0f;
      v -= z;
      bufA[t][j] = z;
    }
  }
  __syncthreads();

  // ---- z1 -> layer_spikes
  for (int idx = tid; idx < T_STEPS * 16; idx += 256) {
    int t = idx >> 4, jv = idx & 15;
    *(float4*)(laySpk + (size_t)t * CHUNK + BATCH * N0 + b * 64 + jv * 4) =
        *(const float4*)&bufA[t][jv * 4];
  }

  // ---- GEMM2: I2[t][o] = sum_j z1[t][j] * W2[o][j] + b2[o]
  for (int idx = tid; idx < T_STEPS * N2; idx += 256) {
    int t = idx / N2, o = idx % N2;
    float a = b2[o];
#pragma unroll
    for (int jq = 0; jq < 16; ++jq) {
      float4 z = *(const float4*)&bufA[t][jq * 4];
      float4 w = *(const float4*)&sW2[o][jq * 4];
      a += z.x * w.x;
      a += z.y * w.y;
      a += z.z * w.z;
      a += z.w * w.w;
    }
    sI2[t][o] = a;
  }
  __syncthreads();

  // ---- scan2 (10 chains)
  if (tid < N2) {
    float v = 0.0f;
    for (int t = 0; t < T_STEPS; ++t) {
      float icur = sI2[t][tid];
      v = v + 0.05f * ((0.0f - v) + icur);
      float z = (v > 1.0f) ? 1.0f : 0.0f;
      v -= z;
      sI2[t][tid] = z;
    }
  }
  __syncthreads();

  // ---- z2 -> out_spikes + layer_spikes
  for (int idx = tid; idx < T_STEPS * N2; idx += 256) {
    int t = idx / N2, o = idx % N2;
    float z = sI2[t][o];
    outSpk[(size_t)t * (BATCH * N2) + b * N2 + o] = z;
    laySpk[(size_t)t * CHUNK + BATCH * (N0 + N1) + b * N2 + o] = z;
  }
}

extern "C" void kernel_launch(void* const* d_in, const int* in_sizes, int n_in,
                              void* d_out, int out_size, void* d_ws, size_t ws_size,
                              hipStream_t stream) {
  const float* inp = (const float*)d_in[0];
  const float* W0  = (const float*)d_in[1];
  const float* b0  = (const float*)d_in[2];
  const float* W1  = (const float*)d_in[3];
  const float* b1  = (const float*)d_in[4];
  const float* W2  = (const float*)d_in[5];
  const float* b2  = (const float*)d_in[6];

  snn_kernel<<<dim3(BATCH), dim3(256), 0, stream>>>(
      inp, W0, b0, W1, b1, W2, b2, (float*)d_out);
}

// Round 4
// 80.047 us; speedup vs baseline: 4.1188x; 4.1188x over previous
//
#include <hip/hip_runtime.h>

#define T_STEPS 100
#define BATCH 256
#define NIN 784
#define N0 64
#define N1 64
#define N2 10
#define CHUNK (BATCH*N0 + BATCH*N1 + BATCH*N2)   // 35328
#define NCHUNKS 49                               // 784 / 16
#define NSPLIT 4
#define PLANE (25600*64)                         // one partial plane (floats)
#define ROWS 25600

// ---------------------------------------------------------------------------
// Kernel 1: partial I0 = X @ W0^T, K-split over blockIdx.y, double-buffered
// LDS (ONE __syncthreads per chunk). Bias added in reduce_kernel.
// ---------------------------------------------------------------------------
__global__ __launch_bounds__(256) void gemm0_kernel(
    const float* __restrict__ X, const float* __restrict__ W0,
    float* __restrict__ P) {
  __shared__ float As[2][16][68];
  __shared__ float Bs[2][16][68];

  const int tid = threadIdx.x;
  const int r0  = blockIdx.x * 64;
  const int s   = blockIdx.y;
  const int tm  = tid >> 4;      // 0..15 -> rows tm*4..tm*4+3
  const int tn  = tid & 15;      // 0..15 -> cols tn*4..tn*4+3
  const int lm  = tid >> 2;      // 0..63 staging row
  const int lkv = tid & 3;       // 0..3  staging k-quad

  const int per  = NCHUNKS / NSPLIT;     // 12
  const int rem  = NCHUNKS % NSPLIT;     // 1
  const int cbeg = s * per + (s < rem ? s : rem);
  const int ccnt = per + (s < rem ? 1 : 0);

  float acc[4][4];
#pragma unroll
  for (int i = 0; i < 4; ++i)
#pragma unroll
    for (int q = 0; q < 4; ++q) acc[i][q] = 0.0f;

  const float* xp = X  + (size_t)(r0 + lm) * NIN + lkv * 4 + cbeg * 16;
  const float* wp = W0 + (size_t)lm * NIN + lkv * 4 + cbeg * 16;

  // prologue: chunk 0 -> buffer 0
  {
    float4 xa = *(const float4*)xp;
    float4 wb = *(const float4*)wp;
    As[0][lkv*4+0][lm] = xa.x;
    As[0][lkv*4+1][lm] = xa.y;
    As[0][lkv*4+2][lm] = xa.z;
    As[0][lkv*4+3][lm] = xa.w;
    Bs[0][lkv*4+0][lm] = wb.x;
    Bs[0][lkv*4+1][lm] = wb.y;
    Bs[0][lkv*4+2][lm] = wb.z;
    Bs[0][lkv*4+3][lm] = wb.w;
  }
  __syncthreads();

  for (int c = 0; c < ccnt; ++c) {
    const int cur = c & 1;
    float4 xa, wb;
    const bool more = (c + 1 < ccnt);
    if (more) {                       // issue next-chunk loads BEFORE compute
      xa = *(const float4*)(xp + (c + 1) * 16);
      wb = *(const float4*)(wp + (c + 1) * 16);
    }
#pragma unroll
    for (int k = 0; k < 16; ++k) {
      float4 a = *(const float4*)&As[cur][k][tm*4];
      float4 b = *(const float4*)&Bs[cur][k][tn*4];
      acc[0][0] += a.x*b.x; acc[0][1] += a.x*b.y; acc[0][2] += a.x*b.z; acc[0][3] += a.x*b.w;
      acc[1][0] += a.y*b.x; acc[1][1] += a.y*b.y; acc[1][2] += a.y*b.z; acc[1][3] += a.y*b.w;
      acc[2][0] += a.z*b.x; acc[2][1] += a.z*b.y; acc[2][2] += a.z*b.z; acc[2][3] += a.z*b.w;
      acc[3][0] += a.w*b.x; acc[3][1] += a.w*b.y; acc[3][2] += a.w*b.z; acc[3][3] += a.w*b.w;
    }
    if (more) {                       // write to OTHER buffer (safe: last read
      const int nxt = cur ^ 1;        // of it was protected by prev sync)
      As[nxt][lkv*4+0][lm] = xa.x;
      As[nxt][lkv*4+1][lm] = xa.y;
      As[nxt][lkv*4+2][lm] = xa.z;
      As[nxt][lkv*4+3][lm] = xa.w;
      Bs[nxt][lkv*4+0][lm] = wb.x;
      Bs[nxt][lkv*4+1][lm] = wb.y;
      Bs[nxt][lkv*4+2][lm] = wb.z;
      Bs[nxt][lkv*4+3][lm] = wb.w;
    }
    __syncthreads();
  }

  float* op = P + (size_t)s * PLANE;
#pragma unroll
  for (int i = 0; i < 4; ++i) {
    const int row = r0 + tm*4 + i;
    float4 o;
    o.x = acc[i][0]; o.y = acc[i][1]; o.z = acc[i][2]; o.w = acc[i][3];
    *(float4*)(op + (size_t)row * N0 + tn*4) = o;
  }
}

// ---------------------------------------------------------------------------
// Kernel 2: I0T[b][t][j] = sum_s P[s][t*256+b][j] + b0[j]   (b-major output)
// Fully coalesced reads; writes 256B rows. 1600 blocks x 256 threads.
// ---------------------------------------------------------------------------
__global__ __launch_bounds__(256) void reduce_kernel(
    const float* __restrict__ P, const float* __restrict__ b0,
    float* __restrict__ I0T) {
  const int f   = blockIdx.x * 256 + threadIdx.x;  // f4 index 0..409599
  const int j4  = f & 15;
  const int row = f >> 4;          // t*256 + b
  const int t   = row >> 8;
  const int b   = row & 255;

  const float4* p = (const float4*)P;
  float4 v  = p[f];
  float4 u1 = p[(size_t)(PLANE/4) * 1 + f];
  float4 u2 = p[(size_t)(PLANE/4) * 2 + f];
  float4 u3 = p[(size_t)(PLANE/4) * 3 + f];
  v.x += u1.x; v.y += u1.y; v.z += u1.z; v.w += u1.w;
  v.x += u2.x; v.y += u2.y; v.z += u2.z; v.w += u2.w;
  v.x += u3.x; v.y += u3.y; v.z += u3.z; v.w += u3.w;
  float4 bv = ((const float4*)b0)[j4];
  v.x += bv.x; v.y += bv.y; v.z += bv.z; v.w += bv.w;

  ((float4*)I0T)[((size_t)b * T_STEPS + t) * 16 + j4] = v;
}

// ---------------------------------------------------------------------------
// Kernel 3: one block per batch element. Staging is a contiguous 25.6 KB
// slab from I0T; scans are pipelined (25 LDS reads batched into registers).
// ---------------------------------------------------------------------------
__global__ __launch_bounds__(256) void fused_kernel(
    const float* __restrict__ I0T,
    const float* __restrict__ W1, const float* __restrict__ b1,
    const float* __restrict__ W2, const float* __restrict__ b2,
    float* __restrict__ out) {
  __shared__ float bufA[T_STEPS][64];   // I0 -> z0 -> I1 -> z1 (in place)
  __shared__ float sW1t[64][66];        // W1 transposed
  __shared__ float sW2[N2][68];
  __shared__ float sI2[T_STEPS][N2];

  const int b   = blockIdx.x;
  const int tid = threadIdx.x;
  const int j   = tid & 63;
  const int tq  = tid >> 6;
  float* outSpk = out;                        // [T][B][10]
  float* laySpk = out + T_STEPS * BATCH * N2; // [T][35328]

  // ---- stage I0 slab (contiguous per block)
  {
    const float4* src = (const float4*)I0T + (size_t)b * (T_STEPS * 16);
    for (int idx = tid; idx < T_STEPS * 16; idx += 256) {
      float4 v = src[idx];
      int t = idx >> 4, j4 = idx & 15;
      *(float4*)&bufA[t][j4 * 4] = v;
    }
  }
  __syncthreads();

  // ---- scan0 (wave 0, pipelined) || W1/W2 staging (waves 1-3)
  if (tq == 0) {
    float v = 0.0f;
#pragma unroll
    for (int g = 0; g < 4; ++g) {
      float ic[25];
#pragma unroll
      for (int i = 0; i < 25; ++i) ic[i] = bufA[g * 25 + i][j];
#pragma unroll
      for (int i = 0; i < 25; ++i) {
        v = v + 0.05f * ((0.0f - v) + ic[i]);
        float z = (v > 1.0f) ? 1.0f : 0.0f;
        v -= z;
        ic[i] = z;
      }
#pragma unroll
      for (int i = 0; i < 25; ++i) bufA[g * 25 + i][j] = ic[i];
    }
  } else {
    for (int idx = tid - 64; idx < 64 * 16; idx += 192) {
      int i = idx >> 4, jv = idx & 15;
      float4 w = *(const float4*)(W1 + (size_t)i * 64 + jv * 4);
      sW1t[jv * 4 + 0][i] = w.x;
      sW1t[jv * 4 + 1][i] = w.y;
      sW1t[jv * 4 + 2][i] = w.z;
      sW1t[jv * 4 + 3][i] = w.w;
    }
    for (int idx = tid - 64; idx < N2 * 16; idx += 192) {
      int o = idx >> 4, jv = idx & 15;
      *(float4*)&sW2[o][jv * 4] = *(const float4*)(W2 + (size_t)o * 64 + jv * 4);
    }
  }
  __syncthreads();

  // ---- z0 -> layer_spikes (async stores), then GEMM1
  for (int idx = tid; idx < T_STEPS * 16; idx += 256) {
    int t = idx >> 4, jv = idx & 15;
    *(float4*)(laySpk + (size_t)t * CHUNK + b * 64 + jv * 4) =
        *(const float4*)&bufA[t][jv * 4];
  }

  float acc[25];
  {
    const float bias = b1[j];
#pragma unroll
    for (int tl = 0; tl < 25; ++tl) acc[tl] = bias;
    const int tb = tq * 25;
    for (int jq = 0; jq < 16; ++jq) {
      float w0 = sW1t[jq * 4 + 0][j];
      float w1 = sW1t[jq * 4 + 1][j];
      float w2 = sW1t[jq * 4 + 2][j];
      float w3 = sW1t[jq * 4 + 3][j];
#pragma unroll
      for (int tl = 0; tl < 25; ++tl) {
        float4 z = *(const float4*)&bufA[tb + tl][jq * 4];
        acc[tl] += z.x * w0;
        acc[tl] += z.y * w1;
        acc[tl] += z.z * w2;
        acc[tl] += z.w * w3;
      }
    }
  }
  __syncthreads();            // all bufA reads complete
#pragma unroll
  for (int tl = 0; tl < 25; ++tl) bufA[tq * 25 + tl][j] = acc[tl];
  __syncthreads();

  // ---- scan1 (wave 0, pipelined)
  if (tq == 0) {
    float v = 0.0f;
#pragma unroll
    for (int g = 0; g < 4; ++g) {
      float ic[25];
#pragma unroll
      for (int i = 0; i < 25; ++i) ic[i] = bufA[g * 25 + i][j];
#pragma unroll
      for (int i = 0; i < 25; ++i) {
        v = v + 0.05f * ((0.0f - v) + ic[i]);
        float z = (v > 1.0f) ? 1.0f : 0.0f;
        v -= z;
        ic[i] = z;
      }
#pragma unroll
      for (int i = 0; i < 25; ++i) bufA[g * 25 + i][j] = ic[i];
    }
  }
  __syncthreads();

  // ---- z1 -> layer_spikes, then GEMM2
  for (int idx = tid; idx < T_STEPS * 16; idx += 256) {
    int t = idx >> 4, jv = idx & 15;
    *(float4*)(laySpk + (size_t)t * CHUNK + BATCH * N0 + b * 64 + jv * 4) =
        *(const float4*)&bufA[t][jv * 4];
  }

  for (int idx = tid; idx < T_STEPS * N2; idx += 256) {
    int t = idx / N2, o = idx % N2;
    float a = b2[o];
#pragma unroll
    for (int jq = 0; jq < 16; ++jq) {
      float4 z = *(const float4*)&bufA[t][jq * 4];
      float4 w = *(const float4*)&sW2[o][jq * 4];
      a += z.x * w.x;
      a += z.y * w.y;
      a += z.z * w.z;
      a += z.w * w.w;
    }
    sI2[t][o] = a;
  }
  __syncthreads();

  // ---- scan2 (10 chains, pipelined)
  if (tid < N2) {
    float v = 0.0f;
#pragma unroll
    for (int g = 0; g < 4; ++g) {
      float ic[25];
#pragma unroll
      for (int i = 0; i < 25; ++i) ic[i] = sI2[g * 25 + i][tid];
#pragma unroll
      for (int i = 0; i < 25; ++i) {
        v = v + 0.05f * ((0.0f - v) + ic[i]);
        float z = (v > 1.0f) ? 1.0f : 0.0f;
        v -= z;
        ic[i] = z;
      }
#pragma unroll
      for (int i = 0; i < 25; ++i) sI2[g * 25 + i][tid] = ic[i];
    }
  }
  __syncthreads();

  // ---- z2 -> out_spikes + layer_spikes
  for (int idx = tid; idx < T_STEPS * N2; idx += 256) {
    int t = idx / N2, o = idx % N2;
    float z = sI2[t][o];
    outSpk[(size_t)t * (BATCH * N2) + b * N2 + o] = z;
    laySpk[(size_t)t * CHUNK + BATCH * (N0 + N1) + b * N2 + o] = z;
  }
}

extern "C" void kernel_launch(void* const* d_in, const int* in_sizes, int n_in,
                              void* d_out, int out_size, void* d_ws, size_t ws_size,
                              hipStream_t stream) {
  const float* inp = (const float*)d_in[0];
  const float* W0  = (const float*)d_in[1];
  const float* b0  = (const float*)d_in[2];
  const float* W1  = (const float*)d_in[3];
  const float* b1  = (const float*)d_in[4];
  const float* W2  = (const float*)d_in[5];
  const float* b2  = (const float*)d_in[6];

  float* P   = (float*)d_ws;                       // 4 planes, 26.2 MB
  float* I0T = P + (size_t)NSPLIT * PLANE;         // 6.55 MB, b-major

  gemm0_kernel<<<dim3(400, NSPLIT), dim3(256), 0, stream>>>(inp, W0, P);
  reduce_kernel<<<dim3(1600), dim3(256), 0, stream>>>(P, b0, I0T);
  fused_kernel<<<dim3(BATCH), dim3(256), 0, stream>>>(I0T, W1, b1, W2, b2,
                                                      (float*)d_out);
}

// Round 5
// 80.031 us; speedup vs baseline: 4.1197x; 1.0002x over previous
//
#include <hip/hip_runtime.h>

#define T_STEPS 100
#define BATCH 256
#define NIN 784
#define N0 64
#define N1 64
#define N2 10
#define CHUNK (BATCH*N0 + BATCH*N1 + BATCH*N2)   // 35328
#define NCHUNKS 49                               // 784 / 16
#define NSPLIT 4
#define PLANE (25600*64)                         // one partial plane (floats)
#define BM 128                                   // gemm0 tile rows

// ---------------------------------------------------------------------------
// Kernel 1: partial I0 = X @ W0^T. Tile 128x64, 128 threads, micro-tile 8x8
// (0.5 B LDS per FLOP vs 1.0 for 4x4 -> halves the LDS-throughput bound).
// K-split over blockIdx.y (same {13,12,12,12} chunk boundaries as before).
// ---------------------------------------------------------------------------
__global__ __launch_bounds__(128) void gemm0_kernel(
    const float* __restrict__ X, const float* __restrict__ W0,
    float* __restrict__ P) {
  __shared__ float As[2][16][132];   // [buf][k][row], pad 132: 2-way max
  __shared__ float Bs[2][16][68];    // [buf][k][col]

  const int tid = threadIdx.x;
  const int r0  = blockIdx.x * BM;
  const int s   = blockIdx.y;
  const int tn  = tid & 7;           // col-group: cols tn*8..+7
  const int tm  = tid >> 3;          // row-group: rows tm*8..+7

  const int per  = NCHUNKS / NSPLIT;     // 12
  const int rem  = NCHUNKS % NSPLIT;     // 1
  const int cbeg = s * per + (s < rem ? s : rem);
  const int ccnt = per + (s < rem ? 1 : 0);

  float acc[8][8];
#pragma unroll
  for (int i = 0; i < 8; ++i)
#pragma unroll
    for (int q = 0; q < 8; ++q) acc[i][q] = 0.0f;

  // staging index maps (f = tid + i*128): row = f>>2, q = f&3 (q = k-quad)
  const int arow = tid >> 2;         // base rows for A staging (4 f4 each)
  const int aq   = tid & 3;

  const float* xbase = X  + (size_t)cbeg * 16 + aq * 4;
  const float* wbase = W0 + (size_t)cbeg * 16 + aq * 4;

  // prologue: chunk 0 -> buffer 0
  {
#pragma unroll
    for (int i = 0; i < 4; ++i) {
      int row = arow + i * 32;       // (tid + i*128)>>2
      float4 v = *(const float4*)(xbase + (size_t)(r0 + row) * NIN);
#pragma unroll
      for (int e = 0; e < 4; ++e) As[0][aq * 4 + e][row] = ((const float*)&v)[e];
    }
#pragma unroll
    for (int i = 0; i < 2; ++i) {
      int row = arow + i * 32;       // 0..63
      float4 v = *(const float4*)(wbase + (size_t)row * NIN);
#pragma unroll
      for (int e = 0; e < 4; ++e) Bs[0][aq * 4 + e][row] = ((const float*)&v)[e];
    }
  }
  __syncthreads();

  for (int c = 0; c < ccnt; ++c) {
    const int cur = c & 1;
    float4 xa[4], wb[2];
    const bool more = (c + 1 < ccnt);
    if (more) {
#pragma unroll
      for (int i = 0; i < 4; ++i) {
        int row = arow + i * 32;
        xa[i] = *(const float4*)(xbase + (size_t)(r0 + row) * NIN + (c + 1) * 16);
      }
#pragma unroll
      for (int i = 0; i < 2; ++i) {
        int row = arow + i * 32;
        wb[i] = *(const float4*)(wbase + (size_t)row * NIN + (c + 1) * 16);
      }
    }
#pragma unroll
    for (int k = 0; k < 16; ++k) {
      float4 a0 = *(const float4*)&As[cur][k][tm * 8];
      float4 a1 = *(const float4*)&As[cur][k][tm * 8 + 4];
      float4 b0 = *(const float4*)&Bs[cur][k][tn * 8];
      float4 b1 = *(const float4*)&Bs[cur][k][tn * 8 + 4];
      float av[8] = {a0.x, a0.y, a0.z, a0.w, a1.x, a1.y, a1.z, a1.w};
      float bv[8] = {b0.x, b0.y, b0.z, b0.w, b1.x, b1.y, b1.z, b1.w};
#pragma unroll
      for (int i = 0; i < 8; ++i)
#pragma unroll
        for (int q = 0; q < 8; ++q) acc[i][q] = fmaf(av[i], bv[q], acc[i][q]);
    }
    if (more) {
      const int nxt = cur ^ 1;
#pragma unroll
      for (int i = 0; i < 4; ++i) {
        int row = arow + i * 32;
#pragma unroll
        for (int e = 0; e < 4; ++e) As[nxt][aq * 4 + e][row] = ((const float*)&xa[i])[e];
      }
#pragma unroll
      for (int i = 0; i < 2; ++i) {
        int row = arow + i * 32;
#pragma unroll
        for (int e = 0; e < 4; ++e) Bs[nxt][aq * 4 + e][row] = ((const float*)&wb[i])[e];
      }
    }
    __syncthreads();
  }

  float* op = P + (size_t)s * PLANE;
#pragma unroll
  for (int i = 0; i < 8; ++i) {
    const int row = r0 + tm * 8 + i;
    float4 o0 = {acc[i][0], acc[i][1], acc[i][2], acc[i][3]};
    float4 o1 = {acc[i][4], acc[i][5], acc[i][6], acc[i][7]};
    *(float4*)(op + (size_t)row * N0 + tn * 8)     = o0;
    *(float4*)(op + (size_t)row * N0 + tn * 8 + 4) = o1;
  }
}

// ---------------------------------------------------------------------------
// Kernel 2: I0T[b][t][j] = sum_s P[s][t*256+b][j] + b0[j]   (b-major output)
// ---------------------------------------------------------------------------
__global__ __launch_bounds__(256) void reduce_kernel(
    const float* __restrict__ P, const float* __restrict__ b0,
    float* __restrict__ I0T) {
  const int f   = blockIdx.x * 256 + threadIdx.x;  // f4 index 0..409599
  const int j4  = f & 15;
  const int row = f >> 4;          // t*256 + b
  const int t   = row >> 8;
  const int b   = row & 255;

  const float4* p = (const float4*)P;
  float4 v  = p[f];
  float4 u1 = p[(size_t)(PLANE/4) * 1 + f];
  float4 u2 = p[(size_t)(PLANE/4) * 2 + f];
  float4 u3 = p[(size_t)(PLANE/4) * 3 + f];
  v.x += u1.x; v.y += u1.y; v.z += u1.z; v.w += u1.w;
  v.x += u2.x; v.y += u2.y; v.z += u2.z; v.w += u2.w;
  v.x += u3.x; v.y += u3.y; v.z += u3.z; v.w += u3.w;
  float4 bv = ((const float4*)b0)[j4];
  v.x += bv.x; v.y += bv.y; v.z += bv.z; v.w += bv.w;

  ((float4*)I0T)[((size_t)b * T_STEPS + t) * 16 + j4] = v;
}

// ---------------------------------------------------------------------------
// Kernel 3: one block per batch element. bufA padded [112][68] (b128-aligned,
// conflict-free, static 7-row t-strips). GEMM1 tiled 4i x 7t per thread.
// ---------------------------------------------------------------------------
__global__ __launch_bounds__(256) void fused_kernel(
    const float* __restrict__ I0T,
    const float* __restrict__ W1, const float* __restrict__ b1,
    const float* __restrict__ W2, const float* __restrict__ b2,
    float* __restrict__ out) {
  __shared__ float bufA[112][68];       // I0 -> z0 -> I1 -> z1 (in place)
  __shared__ float sW1t[64][68];        // W1 transposed [j][i]
  __shared__ float sW2[N2][68];
  __shared__ float sI2[T_STEPS][N2];

  const int b   = blockIdx.x;
  const int tid = threadIdx.x;
  const int j   = tid & 63;
  const int tq  = tid >> 6;
  float* outSpk = out;                        // [T][B][10]
  float* laySpk = out + T_STEPS * BATCH * N2; // [T][35328]

  // ---- stage I0 slab (contiguous per block)
  {
    const float4* src = (const float4*)I0T + (size_t)b * (T_STEPS * 16);
    for (int idx = tid; idx < T_STEPS * 16; idx += 256) {
      float4 v = src[idx];
      int t = idx >> 4, j4 = idx & 15;
      *(float4*)&bufA[t][j4 * 4] = v;
    }
  }
  __syncthreads();

  // ---- scan0 (wave 0, batched) || W1/W2 staging (waves 1-3)
  if (tq == 0) {
    float v = 0.0f;
#pragma unroll
    for (int g = 0; g < 4; ++g) {
      float ic[25];
#pragma unroll
      for (int i = 0; i < 25; ++i) ic[i] = bufA[g * 25 + i][j];
#pragma unroll
      for (int i = 0; i < 25; ++i) {
        v = v + 0.05f * ((0.0f - v) + ic[i]);
        float z = (v > 1.0f) ? 1.0f : 0.0f;
        v -= z;
        ic[i] = z;
      }
#pragma unroll
      for (int i = 0; i < 25; ++i) bufA[g * 25 + i][j] = ic[i];
    }
  } else {
    for (int idx = tid - 64; idx < 64 * 16; idx += 192) {
      int i = idx >> 4, jv = idx & 15;
      float4 w = *(const float4*)(W1 + (size_t)i * 64 + jv * 4);
      sW1t[jv * 4 + 0][i] = w.x;
      sW1t[jv * 4 + 1][i] = w.y;
      sW1t[jv * 4 + 2][i] = w.z;
      sW1t[jv * 4 + 3][i] = w.w;
    }
    for (int idx = tid - 64; idx < N2 * 16; idx += 192) {
      int o = idx >> 4, jv = idx & 15;
      *(float4*)&sW2[o][jv * 4] = *(const float4*)(W2 + (size_t)o * 64 + jv * 4);
    }
  }
  __syncthreads();

  // ---- z0 -> layer_spikes
  for (int idx = tid; idx < T_STEPS * 16; idx += 256) {
    int t = idx >> 4, jv = idx & 15;
    *(float4*)(laySpk + (size_t)t * CHUNK + b * 64 + jv * 4) =
        *(const float4*)&bufA[t][jv * 4];
  }

  // ---- GEMM1: I1[t][i] = b1[i] + sum_j z0[t][j]*W1[i][j]
  // thread = (iq = tid&15 -> i = iq*4..+3, ts = tid>>4 -> t = ts*7..+6)
  // rows 100..111 are junk-compute into pad rows (never emitted).
  const int iq = tid & 15;
  const int ts = tid >> 4;
  float g1[4][7];
  {
    float4 bias = *(const float4*)(b1 + iq * 4);
#pragma unroll
    for (int tt = 0; tt < 7; ++tt) {
      g1[0][tt] = bias.x; g1[1][tt] = bias.y; g1[2][tt] = bias.z; g1[3][tt] = bias.w;
    }
#pragma unroll
    for (int jq = 0; jq < 16; ++jq) {
      float4 z4[7];
#pragma unroll
      for (int tt = 0; tt < 7; ++tt)
        z4[tt] = *(const float4*)&bufA[ts * 7 + tt][jq * 4];
      float4 w4[4];
#pragma unroll
      for (int e = 0; e < 4; ++e)
        w4[e] = *(const float4*)&sW1t[jq * 4 + e][iq * 4];
#pragma unroll
      for (int e = 0; e < 4; ++e) {
#pragma unroll
        for (int tt = 0; tt < 7; ++tt) {
          float zv = ((const float*)&z4[tt])[e];
          g1[0][tt] = fmaf(zv, w4[e].x, g1[0][tt]);
          g1[1][tt] = fmaf(zv, w4[e].y, g1[1][tt]);
          g1[2][tt] = fmaf(zv, w4[e].z, g1[2][tt]);
          g1[3][tt] = fmaf(zv, w4[e].w, g1[3][tt]);
        }
      }
    }
  }
  __syncthreads();            // all z0 reads complete
#pragma unroll
  for (int tt = 0; tt < 7; ++tt) {
    float4 o = {g1[0][tt], g1[1][tt], g1[2][tt], g1[3][tt]};
    *(float4*)&bufA[ts * 7 + tt][iq * 4] = o;
  }
  __syncthreads();

  // ---- scan1 (wave 0, batched)
  if (tq == 0) {
    float v = 0.0f;
#pragma unroll
    for (int g = 0; g < 4; ++g) {
      float ic[25];
#pragma unroll
      for (int i = 0; i < 25; ++i) ic[i] = bufA[g * 25 + i][j];
#pragma unroll
      for (int i = 0; i < 25; ++i) {
        v = v + 0.05f * ((0.0f - v) + ic[i]);
        float z = (v > 1.0f) ? 1.0f : 0.0f;
        v -= z;
        ic[i] = z;
      }
#pragma unroll
      for (int i = 0; i < 25; ++i) bufA[g * 25 + i][j] = ic[i];
    }
  }
  __syncthreads();

  // ---- z1 -> layer_spikes
  for (int idx = tid; idx < T_STEPS * 16; idx += 256) {
    int t = idx >> 4, jv = idx & 15;
    *(float4*)(laySpk + (size_t)t * CHUNK + BATCH * N0 + b * 64 + jv * 4) =
        *(const float4*)&bufA[t][jv * 4];
  }

  // ---- GEMM2: I2[t][o] = b2[o] + sum_j z1[t][j]*W2[o][j]
  for (int idx = tid; idx < T_STEPS * N2; idx += 256) {
    int t = idx / N2, o = idx % N2;
    float a = b2[o];
#pragma unroll
    for (int jq = 0; jq < 16; ++jq) {
      float4 z = *(const float4*)&bufA[t][jq * 4];
      float4 w = *(const float4*)&sW2[o][jq * 4];
      a += z.x * w.x;
      a += z.y * w.y;
      a += z.z * w.z;
      a += z.w * w.w;
    }
    sI2[t][o] = a;
  }
  __syncthreads();

  // ---- scan2 (10 chains, batched)
  if (tid < N2) {
    float v = 0.0f;
#pragma unroll
    for (int g = 0; g < 4; ++g) {
      float ic[25];
#pragma unroll
      for (int i = 0; i < 25; ++i) ic[i] = sI2[g * 25 + i][tid];
#pragma unroll
      for (int i = 0; i < 25; ++i) {
        v = v + 0.05f * ((0.0f - v) + ic[i]);
        float z = (v > 1.0f) ? 1.0f : 0.0f;
        v -= z;
        ic[i] = z;
      }
#pragma unroll
      for (int i = 0; i < 25; ++i) sI2[g * 25 + i][tid] = ic[i];
    }
  }
  __syncthreads();

  // ---- z2 -> out_spikes + layer_spikes
  for (int idx = tid; idx < T_STEPS * N2; idx += 256) {
    int t = idx / N2, o = idx % N2;
    float z = sI2[t][o];
    outSpk[(size_t)t * (BATCH * N2) + b * N2 + o] = z;
    laySpk[(size_t)t * CHUNK + BATCH * (N0 + N1) + b * N2 + o] = z;
  }
}

extern "C" void kernel_launch(void* const* d_in, const int* in_sizes, int n_in,
                              void* d_out, int out_size, void* d_ws, size_t ws_size,
                              hipStream_t stream) {
  const float* inp = (const float*)d_in[0];
  const float* W0  = (const float*)d_in[1];
  const float* b0  = (const float*)d_in[2];
  const float* W1  = (const float*)d_in[3];
  const float* b1  = (const float*)d_in[4];
  const float* W2  = (const float*)d_in[5];
  const float* b2  = (const float*)d_in[6];

  float* P   = (float*)d_ws;                       // 4 planes, 26.2 MB
  float* I0T = P + (size_t)NSPLIT * PLANE;         // 6.55 MB, b-major

  gemm0_kernel<<<dim3(25600 / BM, NSPLIT), dim3(128), 0, stream>>>(inp, W0, P);
  reduce_kernel<<<dim3(1600), dim3(256), 0, stream>>>(P, b0, I0T);
  fused_kernel<<<dim3(BATCH), dim3(256), 0, stream>>>(I0T, W1, b1, W2, b2,
                                                      (float*)d_out);
}